// Round 4
// baseline (647.399 us; speedup 1.0000x reference)
//
#include <hip/hip_runtime.h>

#define NIN   55296
#define CIN   256
#define COUT  256
#define NTH   512
#define NBLK  432   // 2 parities * 216 tiles of 256 rows

typedef __attribute__((ext_vector_type(8))) _Float16 half8;
typedef __attribute__((ext_vector_type(4))) _Float16 half4;
typedef __attribute__((ext_vector_type(4))) float f32x4;

typedef const __attribute__((address_space(1))) void* gp_t;
typedef __attribute__((address_space(3))) void* lp_t;
__device__ __forceinline__ void gload16(const void* g, char* l) {
  __builtin_amdgcn_global_load_lds((gp_t)g, (lp_t)l, 16, 0, 0);
}

// ---------- pre-pass: features f32 -> f16 ----------
__global__ void k_feat_cvt(const float* __restrict__ f, _Float16* __restrict__ o, int n4) {
  int i = blockIdx.x * blockDim.x + threadIdx.x;
  if (i >= n4) return;
  f32x4 v = ((const f32x4*)f)[i];
  half4 r;
  r[0] = (_Float16)v[0]; r[1] = (_Float16)v[1];
  r[2] = (_Float16)v[2]; r[3] = (_Float16)v[3];
  ((half4*)o)[i] = r;
}

// ---------- pre-pass: W f32 [27][cin][cout] -> f16 transposed Wt [27][cout][cin]
__global__ void k_w_cvt(const float* __restrict__ W, _Float16* __restrict__ Wt,
                        float* __restrict__ zeros) {
  int i = blockIdx.x * blockDim.x + threadIdx.x;
  int d   = i >> 16;
  int rem = i & 65535;
  int n   = rem >> 8;
  int k   = rem & 255;
  Wt[i] = (_Float16)W[(d << 16) + (k << 8) + n];
  if (blockIdx.x == 0 && threadIdx.x < 128) zeros[threadIdx.x] = 0.0f;
}

// ---------- main: 256x256 tile, BK=64, A in dbuf LDS (64KB), B global->VGPR dbuf ----------
// LDS: A half d at d*32768: ks0 [256 rows][64B] @+0, ks1 @+16384. orow @65536.
// Per step: __syncthreads (vmcnt(0): A-DMA landed, B regs landed, prev readers done)
//   -> issue A-DMA(s+1) + B-reg loads(s+1) -> a-frag ds_reads -> MFMA (x2 ksubs).
// B lanes (lr,kg) read cout=wn*64+nf*16+lr at k-bytes kk*64+kg*16: 16 full 64B lines/load (L2).
__global__ __launch_bounds__(NTH, 2)
void k_conv8(const _Float16* __restrict__ featb, const _Float16* __restrict__ wt,
             const char* __restrict__ zeros, float* __restrict__ out) {
  extern __shared__ char lds[];
  int* orow = (int*)(lds + 65536);

  const int braw = blockIdx.x;
  const int b    = (braw & 7) * 54 + (braw >> 3);   // bijective XCD swizzle (432 = 8*54)
  const int p    = b & 1;                            // output-voxel parity
  const int tile = b >> 1;                           // 0..215

  const int tid = threadIdx.x;
  const int w   = tid >> 6;
  const int l   = tid & 63;

  // ---- staging geometry: wave w -> k-half ks=w>>2, row-group w4=w&3 (64 rows, 4 gloads)
  const int ks   = w >> 2;
  const int w4   = w & 3;
  const int swz  = ((l & 3) ^ ((l >> 3) & 3)) * 16;  // store-side slot XOR swizzle
  const int stb  = ks * 16384 + w4 * 4096;           // wave's LDS staging base
  const int ks64 = ks * 64;

  int xg[4], yg[4], zg[4];
#pragma unroll
  for (int g = 0; g < 4; ++g) {
    int e = tile * 256 + w4 * 64 + g * 16 + (l >> 2);
    int c = e / 24;
    int zi = e - c * 24;
    int x = c / 48;
    int y = c - x * 48;
    xg[g] = x; yg[g] = y; zg[g] = 2 * zi + ((x + y + p) & 1);
  }
  const char* wtc   = (const char*)wt;
  const char* featc = (const char*)featb;

  // ---- fragment geometry ----
  const int wm = w >> 2, wn = w & 3;
  const int lr = l & 15, kg = l >> 4;
  const int rsw = (kg ^ ((lr >> 1) & 3)) * 16;       // read-side swizzle (matches store)
  const int aRd = (wm * 128 + lr) * 64 + rsw;
  const int bq  = (wn * 64 + lr) * 512 + kg * 16;    // B global lane offset

  // ---- orow table (visible after first __syncthreads) ----
  if (tid < 256) {
    int e = tile * 256 + tid;
    int c = e / 24;
    int zi = e - c * 24;
    int x = c / 48;
    int y = c - x * 48;
    int z = 2 * zi + ((x + y + p) & 1);
    orow[tid] = (x * 48 + y) * 48 + z;
  }

  // ---- offset state ----
  const char* asrc[4];
  const char* wtile;
  auto setoff = [&](int d27) {
    int dx = d27 / 9 - 1, dy = (d27 / 3) % 3 - 1, dz = d27 % 3 - 1;
#pragma unroll
    for (int g = 0; g < 4; ++g) {
      int ux = xg[g] + dx, uy = yg[g] + dy, uz = zg[g] + dz;
      bool v = (unsigned)ux < 48u && (unsigned)uy < 48u && (unsigned)uz < 48u;
      int idx = (ux * 48 + uy) * 24 + (uz >> 1);     // analytic even-lattice row id
      asrc[g] = (v ? (featc + idx * 512) : zeros) + swz + ks64;
    }
    wtile = wtc + d27 * 131072;
  };

  int pn = p ? 0 : 1;                                // offsets with sum-parity p: step 2
  setoff(pn);

  // ---- prologue: A-DMA step0 -> half0; B step0 -> bA ----
  {
    char* Nb = lds + stb;
    gload16(asrc[0], Nb);
    gload16(asrc[1], Nb + 1024);
    gload16(asrc[2], Nb + 2048);
    gload16(asrc[3], Nb + 3072);
  }
  half8 bA[8], bB[8];
  {
    const char* wk = wtile + bq;
#pragma unroll
    for (int nf = 0; nf < 4; ++nf) {
      bA[nf * 2 + 0] = *(const half8*)(wk + nf * 8192);
      bA[nf * 2 + 1] = *(const half8*)(wk + nf * 8192 + 64);
    }
  }

  f32x4 acc[8][4];
#pragma unroll
  for (int i = 0; i < 8; ++i)
#pragma unroll
    for (int j = 0; j < 4; ++j) acc[i][j] = (f32x4)0.0f;

  const int S = p ? 56 : 52;                         // (14 or 13 offsets) * 4 K-steps

#define STEP(sv, HALF, BU, BP) do {                                                \
    __syncthreads();                                                               \
    const char* Ab = lds + (HALF);                                                 \
    const int sn = (sv) + 1;                                                       \
    if (sn < S) {                                                                  \
      if ((sn & 3) == 0) { pn += 2; setoff(pn); }                                  \
      const int kb = (sn & 3) * 128;                                               \
      char* Nb = lds + ((HALF) ^ 32768) + stb;                                     \
      gload16(asrc[0] + kb, Nb);                                                   \
      gload16(asrc[1] + kb, Nb + 1024);                                            \
      gload16(asrc[2] + kb, Nb + 2048);                                            \
      gload16(asrc[3] + kb, Nb + 3072);                                            \
      const char* wk = wtile + kb + bq;                                            \
      _Pragma("unroll")                                                            \
      for (int nf = 0; nf < 4; ++nf) {                                             \
        BP[nf * 2 + 0] = *(const half8*)(wk + nf * 8192);                          \
        BP[nf * 2 + 1] = *(const half8*)(wk + nf * 8192 + 64);                     \
      }                                                                            \
    }                                                                              \
    half8 a[8];                                                                    \
    _Pragma("unroll")                                                              \
    for (int mf = 0; mf < 8; ++mf) a[mf] = *(const half8*)(Ab + aRd + mf * 1024);  \
    __builtin_amdgcn_sched_barrier(0);                                             \
    __builtin_amdgcn_s_setprio(1);                                                 \
    _Pragma("unroll")                                                              \
    for (int mf = 0; mf < 8; ++mf)                                                 \
      _Pragma("unroll")                                                            \
      for (int nf = 0; nf < 4; ++nf)                                               \
        acc[mf][nf] = __builtin_amdgcn_mfma_f32_16x16x32_f16(                      \
            a[mf], BU[nf * 2], acc[mf][nf], 0, 0, 0);                              \
    __builtin_amdgcn_s_setprio(0);                                                 \
    _Pragma("unroll")                                                              \
    for (int mf = 0; mf < 8; ++mf)                                                 \
      a[mf] = *(const half8*)(Ab + 16384 + aRd + mf * 1024);                       \
    __builtin_amdgcn_sched_barrier(0);                                             \
    __builtin_amdgcn_s_setprio(1);                                                 \
    _Pragma("unroll")                                                              \
    for (int mf = 0; mf < 8; ++mf)                                                 \
      _Pragma("unroll")                                                            \
      for (int nf = 0; nf < 4; ++nf)                                               \
        acc[mf][nf] = __builtin_amdgcn_mfma_f32_16x16x32_f16(                      \
            a[mf], BU[nf * 2 + 1], acc[mf][nf], 0, 0, 0);                          \
    __builtin_amdgcn_s_setprio(0);                                                 \
  } while (0)

  for (int s2 = 0; s2 < S; s2 += 2) {
    STEP(s2,     0,     bA, bB);
    STEP(s2 + 1, 32768, bB, bA);
  }
#undef STEP

  // ---- epilogue: C/D layout col=lane&15, row=(lane>>4)*4+i ----
#pragma unroll
  for (int mf = 0; mf < 8; ++mf) {
#pragma unroll
    for (int i = 0; i < 4; ++i) {
      int r = wm * 128 + mf * 16 + kg * 4 + i;
      int o = orow[r];
      float* dst = out + (size_t)o * COUT + wn * 64 + lr;
#pragma unroll
      for (int nf = 0; nf < 4; ++nf) dst[nf * 16] = acc[mf][nf][i];
    }
  }
}

extern "C" void kernel_launch(void* const* d_in, const int* in_sizes, int n_in,
                              void* d_out, int out_size, void* d_ws, size_t ws_size,
                              hipStream_t stream) {
  const float* features = (const float*)d_in[0];
  const float* W = (const float*)d_in[3];
  float* out = (float*)d_out;

  char* ws = (char*)d_ws;
  _Float16* featb = (_Float16*)ws;                      // 28,311,552 B
  _Float16* Wt    = (_Float16*)(ws + 28311552);         //  3,538,944 B
  float*    zeros = (float*)(ws + 28311552 + 3538944);  //       512 B

  (void)hipFuncSetAttribute(reinterpret_cast<const void*>(k_conv8),
                            hipFuncAttributeMaxDynamicSharedMemorySize, 66560);

  {
    int n4 = NIN * CIN / 4;
    k_feat_cvt<<<(n4 + 255) / 256, 256, 0, stream>>>(features, featb, n4);
  }
  k_w_cvt<<<27 * 65536 / 256, 256, 0, stream>>>(W, Wt, zeros);

  k_conv8<<<NBLK, NTH, 66560, stream>>>(featb, Wt, (const char*)zeros, out);
}

// Round 5
// 208.054 us; speedup vs baseline: 3.1117x; 3.1117x over previous
//
#include <hip/hip_runtime.h>

#define NIN   55296
#define CIN   256
#define COUT  256
#define NTH   512
#define NBLK  432   // 2 parities * 216 tiles of 256 rows

typedef __attribute__((ext_vector_type(8))) _Float16 half8;
typedef __attribute__((ext_vector_type(4))) _Float16 half4;
typedef __attribute__((ext_vector_type(4))) float f32x4;

typedef const __attribute__((address_space(1))) void* gp_t;
typedef __attribute__((address_space(3))) void* lp_t;
__device__ __forceinline__ void gload16(const void* g, char* l) {
  __builtin_amdgcn_global_load_lds((gp_t)g, (lp_t)l, 16, 0, 0);
}

// ---------- pre-pass: features f32 -> f16 ----------
__global__ void k_feat_cvt(const float* __restrict__ f, _Float16* __restrict__ o, int n4) {
  int i = blockIdx.x * blockDim.x + threadIdx.x;
  if (i >= n4) return;
  f32x4 v = ((const f32x4*)f)[i];
  half4 r;
  r[0] = (_Float16)v[0]; r[1] = (_Float16)v[1];
  r[2] = (_Float16)v[2]; r[3] = (_Float16)v[3];
  ((half4*)o)[i] = r;
}

// ---------- pre-pass: W f32 [27][cin][cout] -> f16 transposed Wt [27][cout][cin]
__global__ void k_w_cvt(const float* __restrict__ W, _Float16* __restrict__ Wt,
                        float* __restrict__ zeros) {
  int i = blockIdx.x * blockDim.x + threadIdx.x;
  int d   = i >> 16;
  int rem = i & 65535;
  int n   = rem >> 8;
  int k   = rem & 255;
  Wt[i] = (_Float16)W[(d << 16) + (k << 8) + n];
  if (blockIdx.x == 0 && threadIdx.x < 128) zeros[threadIdx.x] = 0.0f;
}

// ---------- main: 8-wave 256x256 tile, BK=64, dbuf LDS, 1 barrier/step, ----------
// ---------- 4-phase interleaved inner schedule (reads of phase k+1 drain under MFMA k)
// LDS half d at d*65536: A_ks0 @0, A_ks1 @16384, B_ks0 @32768, B_ks1 @49152. orow @131072.
// Per step: __syncthreads (vmcnt(0): DMA landed; prev readers done)
//   -> issue 8 DMA gloads (next step) -> ds: b0[0..1], a[0..7], b0[2..3]
//   -> P0: 16 MFMA (a x b0[0,1])            (b0[2,3] drain underneath)
//   -> ds: b1[0..3]
//   -> P1: 16 MFMA (a x b0[2,3]) + rolling reload a[mf]<-ksub1 after last use
//   -> P2: 16 MFMA (a x b1[0,1])  -> P3: 16 MFMA (a x b1[2,3])
__global__ __launch_bounds__(NTH, 2)
void k_conv8(const _Float16* __restrict__ featb, const _Float16* __restrict__ wt,
             const char* __restrict__ zeros, float* __restrict__ out) {
  extern __shared__ char lds[];
  int* orow = (int*)(lds + 131072);

  const int braw = blockIdx.x;
  const int b    = (braw & 7) * 54 + (braw >> 3);   // bijective XCD swizzle (432 = 8*54)
  const int p    = b & 1;                            // output-voxel parity
  const int tile = b >> 1;                           // 0..215

  const int tid = threadIdx.x;
  const int w   = tid >> 6;
  const int l   = tid & 63;

  // ---- staging geometry: thread stages rows R0=rr, R1=128+rr; 4 lanes/row, 16B slots
  const int rr  = w * 16 + (l >> 2);                 // [0,128)
  const int swz = ((l & 3) ^ ((l >> 3) & 3)) * 16;   // slot XOR swizzle

  int xs[2], ys[2], zs[2];
#pragma unroll
  for (int q = 0; q < 2; ++q) {
    int e = tile * 256 + q * 128 + rr;
    int c = e / 24;
    int zi = e - c * 24;
    int x = c / 48;
    int y = c - x * 48;
    xs[q] = x; ys[q] = y; zs[q] = 2 * zi + ((x + y + p) & 1);
  }
  const char* wtc   = (const char*)wt;
  const char* featc = (const char*)featb;
  const int bro0 = rr * 512 + swz;                   // Wt row byte offsets
  const int bro1 = (128 + rr) * 512 + swz;

  // ---- fragment-read geometry ----
  const int wm = w >> 2, wn = w & 3;
  const int lr = l & 15, kg = l >> 4;
  const int rsw = (kg ^ ((lr >> 1) & 3)) * 16;       // read-side swizzle (lane-const)
  const int aRd = (wm * 128 + lr) * 64 + rsw;
  const int bRd = (wn * 64 + lr) * 64 + rsw;

  // ---- orow table (consumed in epilogue; visibility via first __syncthreads) ----
  if (tid < 256) {
    int e = tile * 256 + tid;
    int c = e / 24;
    int zi = e - c * 24;
    int x = c / 48;
    int y = c - x * 48;
    int z = 2 * zi + ((x + y + p) & 1);
    orow[tid] = (x * 48 + y) * 48 + z;
  }

  // ---- prefetch-side offset state ----
  const char* asrc[2];
  const char* wtile;
  auto setoff = [&](int d27) {
    int dx = d27 / 9 - 1, dy = (d27 / 3) % 3 - 1, dz = d27 % 3 - 1;
#pragma unroll
    for (int q = 0; q < 2; ++q) {
      int ux = xs[q] + dx, uy = ys[q] + dy, uz = zs[q] + dz;
      bool v = (unsigned)ux < 48u && (unsigned)uy < 48u && (unsigned)uz < 48u;
      int idx = (ux * 48 + uy) * 24 + (uz >> 1);     // analytic even-lattice row id
      asrc[q] = (v ? (featc + idx * 512) : zeros) + swz;
    }
    wtile = wtc + d27 * 131072;
  };

  int pn = p ? 0 : 1;                                // offsets with sum-parity p, step 2
  setoff(pn);

  // ---- prologue: stage K-step 0 into buffer 0 (8 gloads) ----
  gload16(asrc[0],            lds + 0     + w * 1024);
  gload16(asrc[1],            lds + 8192  + w * 1024);
  gload16(asrc[0] + 64,       lds + 16384 + w * 1024);
  gload16(asrc[1] + 64,       lds + 24576 + w * 1024);
  gload16(wtile + bro0,       lds + 32768 + w * 1024);
  gload16(wtile + bro1,       lds + 40960 + w * 1024);
  gload16(wtile + bro0 + 64,  lds + 49152 + w * 1024);
  gload16(wtile + bro1 + 64,  lds + 57344 + w * 1024);

  f32x4 acc[8][4];
#pragma unroll
  for (int i = 0; i < 8; ++i)
#pragma unroll
    for (int j = 0; j < 4; ++j) acc[i][j] = (f32x4)0.0f;

  const int S = p ? 56 : 52;                         // (14 or 13 offsets) * 4 K-steps

  for (int s = 0; s < S; ++s) {
    __syncthreads();   // vmcnt(0): DMA into buf d landed; d^1 readers done

    const char* Ab = lds + (s & 1) * 65536;
    const char* Bb = Ab + 32768;

    // ---- issue next-step staging into buf d^1 (earliest possible issue) ----
    const int sn = s + 1;
    if (sn < S) {
      if ((sn & 3) == 0) { pn += 2; setoff(pn); }
      char* Nb = lds + (sn & 1) * 65536;
      const int kb = (sn & 3) * 128;
      gload16(asrc[0] + kb,            Nb + 0     + w * 1024);
      gload16(asrc[1] + kb,            Nb + 8192  + w * 1024);
      gload16(asrc[0] + kb + 64,       Nb + 16384 + w * 1024);
      gload16(asrc[1] + kb + 64,       Nb + 24576 + w * 1024);
      gload16(wtile + bro0 + kb,       Nb + 32768 + w * 1024);
      gload16(wtile + bro1 + kb,       Nb + 40960 + w * 1024);
      gload16(wtile + bro0 + kb + 64,  Nb + 49152 + w * 1024);
      gload16(wtile + bro1 + kb + 64,  Nb + 57344 + w * 1024);
    }

    half8 a[8], b0[4], b1[4];

    // ---- reads for P0 (+P1's b-frags queued behind) ----
    b0[0] = *(const half8*)(Bb + bRd);
    b0[1] = *(const half8*)(Bb + bRd + 1024);
#pragma unroll
    for (int mf = 0; mf < 8; ++mf) a[mf] = *(const half8*)(Ab + aRd + mf * 1024);
    b0[2] = *(const half8*)(Bb + bRd + 2048);
    b0[3] = *(const half8*)(Bb + bRd + 3072);
    __builtin_amdgcn_sched_barrier(0);

    // ---- P0: ksub0 x nf{0,1} (b0[2,3] drain underneath) ----
    __builtin_amdgcn_s_setprio(1);
#pragma unroll
    for (int mf = 0; mf < 8; ++mf) {
      acc[mf][0] = __builtin_amdgcn_mfma_f32_16x16x32_f16(a[mf], b0[0], acc[mf][0], 0, 0, 0);
      acc[mf][1] = __builtin_amdgcn_mfma_f32_16x16x32_f16(a[mf], b0[1], acc[mf][1], 0, 0, 0);
    }
    __builtin_amdgcn_s_setprio(0);

    // ---- reads for P2/P3 b-frags (drain under P1) ----
    b1[0] = *(const half8*)(Bb + 16384 + bRd);
    b1[1] = *(const half8*)(Bb + 16384 + bRd + 1024);
    b1[2] = *(const half8*)(Bb + 16384 + bRd + 2048);
    b1[3] = *(const half8*)(Bb + 16384 + bRd + 3072);
    __builtin_amdgcn_sched_barrier(0);

    // ---- P1: ksub0 x nf{2,3}, rolling reload a[mf] <- ksub1 after last use ----
    __builtin_amdgcn_s_setprio(1);
#pragma unroll
    for (int mf = 0; mf < 8; ++mf) {
      acc[mf][2] = __builtin_amdgcn_mfma_f32_16x16x32_f16(a[mf], b0[2], acc[mf][2], 0, 0, 0);
      acc[mf][3] = __builtin_amdgcn_mfma_f32_16x16x32_f16(a[mf], b0[3], acc[mf][3], 0, 0, 0);
      a[mf] = *(const half8*)(Ab + 16384 + aRd + mf * 1024);
    }
    __builtin_amdgcn_s_setprio(0);
    __builtin_amdgcn_sched_barrier(0);

    // ---- P2: ksub1 x nf{0,1} ----
    __builtin_amdgcn_s_setprio(1);
#pragma unroll
    for (int mf = 0; mf < 8; ++mf) {
      acc[mf][0] = __builtin_amdgcn_mfma_f32_16x16x32_f16(a[mf], b1[0], acc[mf][0], 0, 0, 0);
      acc[mf][1] = __builtin_amdgcn_mfma_f32_16x16x32_f16(a[mf], b1[1], acc[mf][1], 0, 0, 0);
    }
    __builtin_amdgcn_s_setprio(0);
    __builtin_amdgcn_sched_barrier(0);

    // ---- P3: ksub1 x nf{2,3} ----
    __builtin_amdgcn_s_setprio(1);
#pragma unroll
    for (int mf = 0; mf < 8; ++mf) {
      acc[mf][2] = __builtin_amdgcn_mfma_f32_16x16x32_f16(a[mf], b1[2], acc[mf][2], 0, 0, 0);
      acc[mf][3] = __builtin_amdgcn_mfma_f32_16x16x32_f16(a[mf], b1[3], acc[mf][3], 0, 0, 0);
    }
    __builtin_amdgcn_s_setprio(0);
  }

  // ---- epilogue: C/D layout col=lane&15, row=(lane>>4)*4+i ----
#pragma unroll
  for (int mf = 0; mf < 8; ++mf) {
#pragma unroll
    for (int i = 0; i < 4; ++i) {
      int r = wm * 128 + mf * 16 + kg * 4 + i;
      int o = orow[r];
      float* dst = out + (size_t)o * COUT + wn * 64 + lr;
#pragma unroll
      for (int nf = 0; nf < 4; ++nf) dst[nf * 16] = acc[mf][nf][i];
    }
  }
}

extern "C" void kernel_launch(void* const* d_in, const int* in_sizes, int n_in,
                              void* d_out, int out_size, void* d_ws, size_t ws_size,
                              hipStream_t stream) {
  const float* features = (const float*)d_in[0];
  const float* W = (const float*)d_in[3];
  float* out = (float*)d_out;

  char* ws = (char*)d_ws;
  _Float16* featb = (_Float16*)ws;                      // 28,311,552 B
  _Float16* Wt    = (_Float16*)(ws + 28311552);         //  3,538,944 B
  float*    zeros = (float*)(ws + 28311552 + 3538944);  //       512 B

  (void)hipFuncSetAttribute(reinterpret_cast<const void*>(k_conv8),
                            hipFuncAttributeMaxDynamicSharedMemorySize, 132096);

  {
    int n4 = NIN * CIN / 4;
    k_feat_cvt<<<(n4 + 255) / 256, 256, 0, stream>>>(features, featb, n4);
  }
  k_w_cvt<<<27 * 65536 / 256, 256, 0, stream>>>(W, Wt, zeros);

  k_conv8<<<NBLK, NTH, 132096, stream>>>(featb, Wt, (const char*)zeros, out);
}